// Round 2
// baseline (307.426 us; speedup 1.0000x reference)
//
#include <hip/hip_runtime.h>
#include <hip/hip_bf16.h>

// AFT-Full fused pipeline, B=8, S=D=1024.
//   qkv = x @ [wq|wk|wv]^T + b        (256^2 8-wave pipelined bf16 MFMA GEMM)
//   E   = exp(k + w)                  (elementwise)
//   vT, EKT = transpose(v), transpose(exp(k))   (per batch)
//   num = E @ v ; den = exp(w) @ exp(k)   (fused in ONE gemm256 launch, z=16)
//   y   = sigmoid(q) * num / den
//   out = y @ out_w^T + out_b         (128^2 GEMM, fp32 store)

typedef float  f32x4  __attribute__((ext_vector_type(4)));
typedef short  short8 __attribute__((ext_vector_type(8)));
typedef __bf16 bf16x8 __attribute__((ext_vector_type(8)));

__device__ __forceinline__ ushort f2bf(float f){
  uint u = __builtin_bit_cast(uint, f);
  u += 0x7fffu + ((u >> 16) & 1u);          // RNE
  return (ushort)(u >> 16);
}
__device__ __forceinline__ float bf2f(ushort u){
  uint v = ((uint)u) << 16;
  return __builtin_bit_cast(float, v);
}

__device__ __forceinline__ void gload16(const ushort* g, ushort* l){
  __builtin_amdgcn_global_load_lds(
      (const __attribute__((address_space(1))) void*)g,
      (__attribute__((address_space(3))) void*)l, 16, 0, 0);
}

__device__ __forceinline__ f32x4 mfma16(short8 a, short8 b, f32x4 c){
  return __builtin_amdgcn_mfma_f32_16x16x32_bf16(
      __builtin_bit_cast(bf16x8, a), __builtin_bit_cast(bf16x8, b), c, 0, 0, 0);
}

// ---------------------------------------------------------------------------
// gemm256: C[M,N](bf16) = A[M,1024] @ B[N,1024]^T (+bias), K=1024 fixed.
// 256x256 tile, 8 waves (2Mx4N), BK=32, quad-buffered LDS (128 KiB),
// global_load_lds w=16 with source-side XOR pre-swizzle ((row>>1)&3),
// counted vmcnt(8) at K-tile boundaries (3 tiles prefetch depth),
// raw s_barrier + sched_barrier(0) fences, setprio around MFMA clusters.
// Two (A,B,C,stride) sides selected by blockIdx.z vs zsplit (num/den fusion).
// ---------------------------------------------------------------------------
__global__ __launch_bounds__(512, 2) void gemm256(
    const ushort* __restrict__ A0, long sA0,
    const ushort* __restrict__ B0, long sB0,
    ushort* __restrict__ C0, long sC0,
    const ushort* __restrict__ A1, long sA1,
    const ushort* __restrict__ B1, long sB1,
    ushort* __restrict__ C1, long sC1,
    const float* __restrict__ bias, int N, int zsplit)
{
  __shared__ ushort sh[65536] __attribute__((aligned(16)));   // 128 KiB

  const int tid  = threadIdx.x;
  const int lane = tid & 63;
  const int wid  = tid >> 6;
  const int wm   = wid >> 2;            // 0..1
  const int wn   = wid & 3;             // 0..3
  const long tileM = (long)blockIdx.y * 256;
  const long tileN = (long)blockIdx.x * 256;
  const int  z = blockIdx.z;

  const ushort* Ab; const ushort* Bb; ushort* Cb;
  if (z < zsplit) {
    Ab = A0 + (long)z * sA0; Bb = B0 + (long)z * sB0; Cb = C0 + (long)z * sC0;
  } else {
    int z1 = z - zsplit;
    Ab = A1 + (long)z1 * sA1; Bb = B1 + (long)z1 * sB1; Cb = C1 + (long)z1 * sC1;
  }
  Ab += tileM * 1024;
  Bb += tileN * 1024;

  // staging addressing (t-independent): 1024 chunks of 16B per operand tile,
  // 2 per thread; LDS dest linear, global col chunk pre-swizzled.
  long gA[2]; int lO[2];
#pragma unroll
  for (int j = 0; j < 2; ++j) {
    int ch  = j * 512 + tid;            // wave-contiguous
    int row = ch >> 2, c = ch & 3;
    int cs  = c ^ ((row >> 1) & 3);
    gA[j] = (long)row * 1024 + cs * 8;
    lO[j] = ch * 8;
  }

  f32x4 acc[8][4];
#pragma unroll
  for (int i = 0; i < 8; ++i)
#pragma unroll
    for (int j = 0; j < 4; ++j) acc[i][j] = (f32x4)0.f;

  // fragment read offsets (within a buffer), swizzle XOR on read
  const int sw  = ((lane & 15) >> 1) & 3;
  const int kq  = lane >> 4;                          // 0..3
  const int aoff = (wm * 128 + (lane & 15)) * 32 + ((kq ^ sw) * 8);
  const int boff = (wn * 64  + (lane & 15)) * 32 + ((kq ^ sw) * 8);

  auto stage = [&](int t) {
    int b = (t & 3) * 8192, kt = t * 32;
#pragma unroll
    for (int j = 0; j < 2; ++j) {
      gload16(Ab + gA[j] + kt, &sh[b + lO[j]]);
      gload16(Bb + gA[j] + kt, &sh[32768 + b + lO[j]]);
    }
  };

  // prologue: tiles 0,1,2 in flight (12 loads) -> wait tile 0 (vmcnt 8)
  stage(0); stage(1); stage(2);
  asm volatile("s_waitcnt vmcnt(8)" ::: "memory");
  __builtin_amdgcn_s_barrier();
  __builtin_amdgcn_sched_barrier(0);

  for (int t = 0; t < 32; ++t) {
    if (t + 3 < 32) stage(t + 3);       // into buf (t+3)&3 == (t-1)&3

    const ushort* Al = &sh[(t & 3) * 8192];
    const ushort* Bl = &sh[32768 + (t & 3) * 8192];

    short8 bf[4], af0[4], af1[4];
#pragma unroll
    for (int j = 0; j < 4; ++j) bf[j]  = *(const short8*)&Bl[boff + j * 512];
#pragma unroll
    for (int j = 0; j < 4; ++j) af0[j] = *(const short8*)&Al[aoff + j * 512];
    __builtin_amdgcn_s_barrier();
    __builtin_amdgcn_s_setprio(1);
#pragma unroll
    for (int fi = 0; fi < 4; ++fi)
#pragma unroll
      for (int fj = 0; fj < 4; ++fj)
        acc[fi][fj] = mfma16(af0[fi], bf[fj], acc[fi][fj]);
    __builtin_amdgcn_s_setprio(0);
    __builtin_amdgcn_s_barrier();

#pragma unroll
    for (int j = 0; j < 4; ++j) af1[j] = *(const short8*)&Al[aoff + (4 + j) * 512];
    __builtin_amdgcn_s_barrier();
    __builtin_amdgcn_s_setprio(1);
#pragma unroll
    for (int fi = 0; fi < 4; ++fi)
#pragma unroll
      for (int fj = 0; fj < 4; ++fj)
        acc[4 + fi][fj] = mfma16(af1[fi], bf[fj], acc[4 + fi][fj]);
    __builtin_amdgcn_s_setprio(0);

    // boundary: ensure tile t+1 resident everywhere before next iter's reads
    if (t < 29)       asm volatile("s_waitcnt vmcnt(8)" ::: "memory");
    else if (t == 29) asm volatile("s_waitcnt vmcnt(4)" ::: "memory");
    else if (t == 30) asm volatile("s_waitcnt vmcnt(0)" ::: "memory");
    if (t < 31) {
      __builtin_amdgcn_s_barrier();
      __builtin_amdgcn_sched_barrier(0);
    }
  }

  // epilogue: lane l, reg r -> row=(l>>4)*4+r, col=l&15 within 16x16 frag
#pragma unroll
  for (int fj = 0; fj < 4; ++fj) {
    long gn = tileN + wn * 64 + fj * 16 + (lane & 15);
    float bv = bias ? bias[gn] : 0.f;
#pragma unroll
    for (int fi = 0; fi < 8; ++fi) {
      long gm0 = tileM + wm * 128 + fi * 16 + (lane >> 4) * 4;
#pragma unroll
      for (int r = 0; r < 4; ++r)
        Cb[(gm0 + r) * (long)N + gn] = f2bf(acc[fi][fj][r] + bv);
    }
  }
}

// ---------------------------------------------------------------------------
// 128^2 BT GEMM (known-good m97 structure) — kept for the fp32-store out-proj.
// ---------------------------------------------------------------------------
template<int EPI>
__global__ __launch_bounds__(256) void gemm_bt(
    const ushort* __restrict__ A, const ushort* __restrict__ B,
    void* __restrict__ C, const float* __restrict__ bias,
    int N, int K, long sA, long sB, long sC)
{
  __shared__ ushort As[128 * 64] __attribute__((aligned(16)));
  __shared__ ushort Bs[128 * 64] __attribute__((aligned(16)));

  const int tid  = threadIdx.x;
  const int lane = tid & 63;
  const int wid  = tid >> 6;
  const int wm   = wid >> 1;
  const int wn   = wid & 1;
  const long z   = blockIdx.z;
  const long tileM = (long)blockIdx.y * 128;
  const long tileN = (long)blockIdx.x * 128;

  const ushort* Ab = A + z * sA + tileM * K;
  const ushort* Bb = B + z * sB + tileN * K;

  long gOff[4]; int lOff[4];
#pragma unroll
  for (int j = 0; j < 4; ++j) {
    int chunk = j * 256 + tid;
    int row   = chunk >> 3;
    int c16   = (chunk & 7) ^ (row & 7);
    gOff[j]   = (long)row * K + c16 * 8;
    lOff[j]   = chunk * 8;
  }

  f32x4 acc[4][4];
#pragma unroll
  for (int i = 0; i < 4; ++i)
#pragma unroll
    for (int j = 0; j < 4; ++j) acc[i][j] = (f32x4)0.f;

  const int rA0 = wm * 64 + (lane & 15);
  const int rB0 = wn * 64 + (lane & 15);
  const int cw0 = lane >> 4;

  for (int kt = 0; kt < K; kt += 64) {
    __syncthreads();
#pragma unroll
    for (int j = 0; j < 4; ++j) {
      gload16(Ab + gOff[j] + kt, &As[lOff[j]]);
      gload16(Bb + gOff[j] + kt, &Bs[lOff[j]]);
    }
    __syncthreads();

    short8 af[4][2], bf[4][2];
#pragma unroll
    for (int f = 0; f < 4; ++f) {
      int ra = rA0 + f * 16;
      int rb = rB0 + f * 16;
#pragma unroll
      for (int kk = 0; kk < 2; ++kk) {
        af[f][kk] = *(const short8*)&As[ra * 64 + (((kk * 4 + cw0) ^ (ra & 7)) * 8)];
        bf[f][kk] = *(const short8*)&Bs[rb * 64 + (((kk * 4 + cw0) ^ (rb & 7)) * 8)];
      }
    }
#pragma unroll
    for (int kk = 0; kk < 2; ++kk)
#pragma unroll
      for (int fi = 0; fi < 4; ++fi)
#pragma unroll
        for (int fj = 0; fj < 4; ++fj)
          acc[fi][fj] = mfma16(af[fi][kk], bf[fj][kk], acc[fi][fj]);
  }

#pragma unroll
  for (int fi = 0; fi < 4; ++fi) {
    long gm0 = tileM + wm * 64 + fi * 16 + (lane >> 4) * 4;
#pragma unroll
    for (int fj = 0; fj < 4; ++fj) {
      long gn = tileN + wn * 64 + fj * 16 + (lane & 15);
      float bv = bias ? bias[gn] : 0.f;
      if (EPI == 0) {
        ushort* Cp = (ushort*)C + z * sC;
#pragma unroll
        for (int r = 0; r < 4; ++r)
          Cp[(gm0 + r) * (long)N + gn] = f2bf(acc[fi][fj][r] + bv);
      } else {
        float* Cp = (float*)C + z * sC;
#pragma unroll
        for (int r = 0; r < 4; ++r)
          Cp[(gm0 + r) * (long)N + gn] = acc[fi][fj][r] + bv;
      }
    }
  }
}

// ---------------------------------------------------------------------------
// elementwise / prep kernels
// ---------------------------------------------------------------------------
__global__ void cvt_x(const float* __restrict__ in, ushort* __restrict__ out){
  long i4 = ((long)blockIdx.x * 256 + threadIdx.x) * 4;
  float4 v = *(const float4*)&in[i4];
  ushort4 o;
  o.x = f2bf(v.x); o.y = f2bf(v.y); o.z = f2bf(v.z); o.w = f2bf(v.w);
  *(ushort4*)&out[i4] = o;
}

__global__ void prep(const float* __restrict__ wq, const float* __restrict__ wk,
                     const float* __restrict__ wv, const float* __restrict__ ow,
                     const float* __restrict__ w,
                     const float* __restrict__ bq, const float* __restrict__ bk,
                     const float* __restrict__ bv,
                     ushort* __restrict__ wcat, ushort* __restrict__ owb,
                     ushort* __restrict__ ewb, float* __restrict__ bcat)
{
  long i4 = ((long)blockIdx.x * 256 + threadIdx.x) * 4;
  const long MB = 1048576;
  if (i4 < 3 * MB) {
    const float* src = (i4 < MB) ? wq : (i4 < 2 * MB ? wk : wv);
    long off = i4 & (MB - 1);
    float4 v = *(const float4*)&src[off];
    ushort4 o; o.x=f2bf(v.x); o.y=f2bf(v.y); o.z=f2bf(v.z); o.w=f2bf(v.w);
    *(ushort4*)&wcat[i4] = o;
  } else if (i4 < 4 * MB) {
    long off = i4 - 3 * MB;
    float4 v = *(const float4*)&ow[off];
    ushort4 o; o.x=f2bf(v.x); o.y=f2bf(v.y); o.z=f2bf(v.z); o.w=f2bf(v.w);
    *(ushort4*)&owb[off] = o;
  } else if (i4 < 5 * MB) {
    long off = i4 - 4 * MB;
    float4 v = *(const float4*)&w[off];
    ushort4 o;
    o.x=f2bf(expf(v.x)); o.y=f2bf(expf(v.y)); o.z=f2bf(expf(v.z)); o.w=f2bf(expf(v.w));
    *(ushort4*)&ewb[off] = o;
  } else {
    long i = i4 - 5 * MB;
    if (i < 3072) {
      const float* src = (i < 1024) ? bq : (i < 2048 ? bk : bv);
      long off = i & 1023;
      *(float4*)&bcat[i] = *(const float4*)&src[off];
    }
  }
}

__global__ void ew_E(const ushort* __restrict__ qkv, const float* __restrict__ w,
                     ushort* __restrict__ E)
{
  long e4 = ((long)blockIdx.x * 256 + threadIdx.x) * 4;
  long m = e4 >> 10;
  int  j = (int)(e4 & 1023);
  int  s = (int)(m & 1023);
  ushort4 kv = *(const ushort4*)&qkv[m * 3072 + 1024 + j];
  float4  wv = *(const float4*)&w[(long)s * 1024 + j];
  ushort4 o;
  o.x = f2bf(expf(bf2f(kv.x) + wv.x));
  o.y = f2bf(expf(bf2f(kv.y) + wv.y));
  o.z = f2bf(expf(bf2f(kv.z) + wv.z));
  o.w = f2bf(expf(bf2f(kv.w) + wv.w));
  *(ushort4*)&E[e4] = o;
}

template<bool DOEXP>
__global__ void transpose_seg(const ushort* __restrict__ qkv,
                              ushort* __restrict__ dst, int colOff)
{
  __shared__ float tile[32][33];
  int b  = blockIdx.z;
  int s0 = blockIdx.y * 32, d0 = blockIdx.x * 32;
  int tx = threadIdx.x, ty = threadIdx.y;
#pragma unroll
  for (int i = 0; i < 4; ++i) {
    int s = s0 + ty + i * 8;
    float f = bf2f(qkv[((long)(b * 1024 + s)) * 3072 + colOff + d0 + tx]);
    if (DOEXP) f = expf(f);
    tile[ty + i * 8][tx] = f;
  }
  __syncthreads();
#pragma unroll
  for (int i = 0; i < 4; ++i) {
    int d = d0 + ty + i * 8;
    dst[((long)b * 1024 + d) * 1024 + s0 + tx] = f2bf(tile[tx][ty + i * 8]);
  }
}

__global__ void ew_y(const ushort* __restrict__ qkv, const ushort* __restrict__ num,
                     const ushort* __restrict__ den, ushort* __restrict__ y)
{
  long e4 = ((long)blockIdx.x * 256 + threadIdx.x) * 4;
  long m = e4 >> 10;
  int  d = (int)(e4 & 1023);
  ushort4 q4 = *(const ushort4*)&qkv[m * 3072 + d];
  ushort4 n4 = *(const ushort4*)&num[e4];
  ushort4 d4 = *(const ushort4*)&den[e4];
  ushort4 o;
  { float q = bf2f(q4.x), s = 1.f / (1.f + expf(-q)); o.x = f2bf(s * bf2f(n4.x) / bf2f(d4.x)); }
  { float q = bf2f(q4.y), s = 1.f / (1.f + expf(-q)); o.y = f2bf(s * bf2f(n4.y) / bf2f(d4.y)); }
  { float q = bf2f(q4.z), s = 1.f / (1.f + expf(-q)); o.z = f2bf(s * bf2f(n4.z) / bf2f(d4.z)); }
  { float q = bf2f(q4.w), s = 1.f / (1.f + expf(-q)); o.w = f2bf(s * bf2f(n4.w) / bf2f(d4.w)); }
  *(ushort4*)&y[e4] = o;
}

// ---------------------------------------------------------------------------
extern "C" void kernel_launch(void* const* d_in, const int* in_sizes, int n_in,
                              void* d_out, int out_size, void* d_ws, size_t ws_size,
                              hipStream_t stream)
{
  const float* x     = (const float*)d_in[0];
  const float* wq_w  = (const float*)d_in[1];
  const float* wq_b  = (const float*)d_in[2];
  const float* wk_w  = (const float*)d_in[3];
  const float* wk_b  = (const float*)d_in[4];
  const float* wv_w  = (const float*)d_in[5];
  const float* wv_b  = (const float*)d_in[6];
  const float* w     = (const float*)d_in[7];
  const float* out_w = (const float*)d_in[8];
  const float* out_b = (const float*)d_in[9];
  float* out = (float*)d_out;

  const long MB = 1048576;
  char* ws = (char*)d_ws;
  size_t o = 0;
  auto alloc = [&](size_t bytes){ size_t r = o; o += (bytes + 255) & ~(size_t)255; return r; };

  ushort* xb   = (ushort*)(ws + alloc(8192 * 1024 * 2));
  ushort* wcat = (ushort*)(ws + alloc(3072 * 1024 * 2));
  ushort* owb  = (ushort*)(ws + alloc(1024 * 1024 * 2));
  ushort* ewb  = (ushort*)(ws + alloc(1024 * 1024 * 2));
  float*  bcat = (float*) (ws + alloc(3072 * 4));
  ushort* qkvb = (ushort*)(ws + alloc(8192 * 3072 * 2));
  ushort* Eb   = (ushort*)(ws + alloc(8 * MB * 2));
  ushort* vTb  = (ushort*)(ws + alloc(8 * MB * 2));
  ushort* EKTb = (ushort*)(ws + alloc(8 * MB * 2));
  ushort* numb = (ushort*)(ws + alloc(8 * MB * 2));
  ushort* denb = (ushort*)(ws + alloc(8 * MB * 2));
  ushort* yb   = (ushort*)(ws + alloc(8 * MB * 2));
  (void)ws_size; (void)in_sizes; (void)n_in; (void)out_size;

  cvt_x<<<8192, 256, 0, stream>>>(x, xb);
  prep<<<5123, 256, 0, stream>>>(wq_w, wk_w, wv_w, out_w, w,
                                 wq_b, wk_b, wv_b, wcat, owb, ewb, bcat);

  // qkv = x @ wcat^T + bcat : M=8192 N=3072 K=1024  (384 blocks)
  gemm256<<<dim3(12, 32, 1), 512, 0, stream>>>(
      xb, 0, wcat, 0, qkvb, 0,
      xb, 0, wcat, 0, qkvb, 0,
      bcat, 3072, 1);

  ew_E<<<8192, 256, 0, stream>>>(qkvb, w, Eb);
  transpose_seg<false><<<dim3(32, 32, 8), dim3(32, 8), 0, stream>>>(qkvb, vTb, 2048);
  transpose_seg<true ><<<dim3(32, 32, 8), dim3(32, 8), 0, stream>>>(qkvb, EKTb, 1024);

  // fused: z<8 -> num[b] = E[b] @ vT[b]^T ; z>=8 -> den[b] = exp(w) @ EKT[b]^T
  // 256 blocks -> full GPU
  gemm256<<<dim3(4, 4, 16), 512, 0, stream>>>(
      Eb,  MB, vTb,  MB, numb, MB,
      ewb, 0,  EKTb, MB, denb, MB,
      nullptr, 1024, 8);

  ew_y<<<8192, 256, 0, stream>>>(qkvb, numb, denb, yb);

  // out = y @ out_w^T + out_b : M=8192 N=1024 K=1024, fp32 store (512 blocks)
  gemm_bt<1><<<dim3(8, 64, 1), 256, 0, stream>>>(
      yb, owb, out, out_b, 1024, 1024, 0, 0, 0);
}

// Round 4
// 288.140 us; speedup vs baseline: 1.0669x; 1.0669x over previous
//
#include <hip/hip_runtime.h>
#include <hip/hip_bf16.h>

// AFT-Full fused pipeline, B=8, S=D=1024.  6 launches:
//   prep_all : x->bf16, weights->bf16, exp(w)->bf16, biases
//   gemm_bt  : qkv = x @ [wq|wk|wv]^T + b   (M=8192,N=3072,K=1024)
//   mid      : E=exp(k+w), vT, EKT=exp(k)^T (per batch)
//   gemm_bt  : num = E @ vT^T (z<8) | den = exp(w) @ EKT^T (z>=8), one launch
//   ew_y     : y = sigmoid(q) * num / den
//   gemm_bt  : out = y @ out_w^T + out_b    (fp32 store)

typedef float  f32x4  __attribute__((ext_vector_type(4)));
typedef short  short8 __attribute__((ext_vector_type(8)));
typedef __bf16 bf16x8 __attribute__((ext_vector_type(8)));

__device__ __forceinline__ ushort f2bf(float f){
  uint u = __builtin_bit_cast(uint, f);
  u += 0x7fffu + ((u >> 16) & 1u);          // RNE
  return (ushort)(u >> 16);
}
__device__ __forceinline__ float bf2f(ushort u){
  uint v = ((uint)u) << 16;
  return __builtin_bit_cast(float, v);
}

__device__ __forceinline__ void gload16(const ushort* g, ushort* l){
  __builtin_amdgcn_global_load_lds(
      (const __attribute__((address_space(1))) void*)g,
      (__attribute__((address_space(3))) void*)l, 16, 0, 0);
}

__device__ __forceinline__ f32x4 mfma16(short8 a, short8 b, f32x4 c){
  return __builtin_amdgcn_mfma_f32_16x16x32_bf16(
      __builtin_bit_cast(bf16x8, a), __builtin_bit_cast(bf16x8, b), c, 0, 0, 0);
}

// ---------------------------------------------------------------------------
// BT GEMM: C[M,N] = A[M,K] @ B[N,K]^T (+bias[n]).  128x128 tile, 4 waves,
// BK=64, global_load_lds w=16 with source-side XOR pre-swizzle (measured
// 0 bank conflicts), bijective XCD-aware block swizzle (T1, m204 variant).
// Dual (A,B,C,bias) sides selected by swizzled z vs zsplit (num/den fusion).
// EPI=0: bf16 store; EPI=1: fp32 store.
// ---------------------------------------------------------------------------
template<int EPI>
__global__ __launch_bounds__(256) void gemm_bt(
    const ushort* __restrict__ A0, long sA0,
    const ushort* __restrict__ B0, long sB0,
    void* __restrict__ C0, long sC0, const float* __restrict__ bias0,
    const ushort* __restrict__ A1, long sA1,
    const ushort* __restrict__ B1, long sB1,
    void* __restrict__ C1, long sC1, const float* __restrict__ bias1,
    int N, int K, int zsplit)
{
  __shared__ ushort As[128 * 64] __attribute__((aligned(16)));
  __shared__ ushort Bs[128 * 64] __attribute__((aligned(16)));

  // ---- bijective XCD-aware block swizzle (m204): dispatch slot -> work tile
  const int nx = gridDim.x, ny = gridDim.y;
  const long nwg = (long)nx * ny * gridDim.z;
  const long lid = ((long)blockIdx.z * ny + blockIdx.y) * nx + blockIdx.x;
  const long q8 = nwg >> 3, r8 = nwg & 7;
  const long xcd = lid & 7, idx = lid >> 3;
  const long sid = (xcd < r8 ? xcd * (q8 + 1) : r8 * (q8 + 1) + (xcd - r8) * q8) + idx;
  const int bx = (int)(sid % nx);
  const long t1 = sid / nx;
  const int by = (int)(t1 % ny);
  const int bz = (int)(t1 / ny);

  const int tid  = threadIdx.x;
  const int lane = tid & 63;
  const int wid  = tid >> 6;
  const int wm   = wid >> 1;
  const int wn   = wid & 1;
  const long tileM = (long)by * 128;
  const long tileN = (long)bx * 128;

  const ushort* Ab; const ushort* Bb; void* Cb; const float* bias;
  if (bz < zsplit) {
    Ab = A0 + (long)bz * sA0; Bb = B0 + (long)bz * sB0;
    Cb = (char*)C0 + (long)bz * sC0 * (EPI ? 4 : 2); bias = bias0;
  } else {
    long z1 = bz - zsplit;
    Ab = A1 + z1 * sA1; Bb = B1 + z1 * sB1;
    Cb = (char*)C1 + z1 * sC1 * (EPI ? 4 : 2); bias = bias1;
  }
  Ab += tileM * K;
  Bb += tileN * K;

  long gOff[4]; int lOff[4];
#pragma unroll
  for (int j = 0; j < 4; ++j) {
    int chunk = j * 256 + tid;           // wave-contiguous
    int row   = chunk >> 3;              // 0..127
    int c16   = (chunk & 7) ^ (row & 7); // pre-swizzled source column chunk
    gOff[j]   = (long)row * K + c16 * 8;
    lOff[j]   = chunk * 8;
  }

  f32x4 acc[4][4];
#pragma unroll
  for (int i = 0; i < 4; ++i)
#pragma unroll
    for (int j = 0; j < 4; ++j) acc[i][j] = (f32x4)0.f;

  const int rA0 = wm * 64 + (lane & 15);
  const int rB0 = wn * 64 + (lane & 15);
  const int cw0 = lane >> 4;

  for (int kt = 0; kt < K; kt += 64) {
    __syncthreads();
#pragma unroll
    for (int j = 0; j < 4; ++j) {
      gload16(Ab + gOff[j] + kt, &As[lOff[j]]);
      gload16(Bb + gOff[j] + kt, &Bs[lOff[j]]);
    }
    __syncthreads();

    short8 af[4][2], bf[4][2];
#pragma unroll
    for (int f = 0; f < 4; ++f) {
      int ra = rA0 + f * 16;
      int rb = rB0 + f * 16;
#pragma unroll
      for (int kk = 0; kk < 2; ++kk) {
        af[f][kk] = *(const short8*)&As[ra * 64 + (((kk * 4 + cw0) ^ (ra & 7)) * 8)];
        bf[f][kk] = *(const short8*)&Bs[rb * 64 + (((kk * 4 + cw0) ^ (rb & 7)) * 8)];
      }
    }
#pragma unroll
    for (int kk = 0; kk < 2; ++kk)
#pragma unroll
      for (int fi = 0; fi < 4; ++fi)
#pragma unroll
        for (int fj = 0; fj < 4; ++fj)
          acc[fi][fj] = mfma16(af[fi][kk], bf[fj][kk], acc[fi][fj]);
  }

  // epilogue: lane l, reg r -> row=(l>>4)*4+r, col=l&15 within 16x16 frag
#pragma unroll
  for (int fi = 0; fi < 4; ++fi) {
    long gm0 = tileM + wm * 64 + fi * 16 + (lane >> 4) * 4;
#pragma unroll
    for (int fj = 0; fj < 4; ++fj) {
      long gn = tileN + wn * 64 + fj * 16 + (lane & 15);
      float bv = bias ? bias[gn] : 0.f;
      if (EPI == 0) {
        ushort* Cp = (ushort*)Cb;
#pragma unroll
        for (int r = 0; r < 4; ++r)
          Cp[(gm0 + r) * (long)N + gn] = f2bf(acc[fi][fj][r] + bv);
      } else {
        float* Cp = (float*)Cb;
#pragma unroll
        for (int r = 0; r < 4; ++r)
          Cp[(gm0 + r) * (long)N + gn] = acc[fi][fj][r] + bv;
      }
    }
  }
}

// ---------------------------------------------------------------------------
// prep_all: x -> bf16 (8M elems), [wq|wk|wv] -> bf16, out_w -> bf16,
// exp(w) -> bf16, biases -> bcat.  One launch.
// ---------------------------------------------------------------------------
__global__ void prep_all(const float* __restrict__ x,
                         const float* __restrict__ wq, const float* __restrict__ wk,
                         const float* __restrict__ wv, const float* __restrict__ ow,
                         const float* __restrict__ w,
                         const float* __restrict__ bq, const float* __restrict__ bk,
                         const float* __restrict__ bv,
                         ushort* __restrict__ xb,
                         ushort* __restrict__ wcat, ushort* __restrict__ owb,
                         ushort* __restrict__ ewb, float* __restrict__ bcat)
{
  const long MB = 1048576;
  long i4 = ((long)blockIdx.x * 256 + threadIdx.x) * 4;
  if (i4 < 8 * MB) {
    float4 v = *(const float4*)&x[i4];
    ushort4 o; o.x=f2bf(v.x); o.y=f2bf(v.y); o.z=f2bf(v.z); o.w=f2bf(v.w);
    *(ushort4*)&xb[i4] = o;
    return;
  }
  long j4 = i4 - 8 * MB;
  if (j4 < 3 * MB) {
    const float* src = (j4 < MB) ? wq : (j4 < 2 * MB ? wk : wv);
    long off = j4 & (MB - 1);
    float4 v = *(const float4*)&src[off];
    ushort4 o; o.x=f2bf(v.x); o.y=f2bf(v.y); o.z=f2bf(v.z); o.w=f2bf(v.w);
    *(ushort4*)&wcat[j4] = o;
  } else if (j4 < 4 * MB) {
    long off = j4 - 3 * MB;
    float4 v = *(const float4*)&ow[off];
    ushort4 o; o.x=f2bf(v.x); o.y=f2bf(v.y); o.z=f2bf(v.z); o.w=f2bf(v.w);
    *(ushort4*)&owb[off] = o;
  } else if (j4 < 5 * MB) {
    long off = j4 - 4 * MB;
    float4 v = *(const float4*)&w[off];
    ushort4 o;
    o.x=f2bf(expf(v.x)); o.y=f2bf(expf(v.y)); o.z=f2bf(expf(v.z)); o.w=f2bf(expf(v.w));
    *(ushort4*)&ewb[off] = o;
  } else {
    long i = j4 - 5 * MB;
    if (i < 3072) {
      const float* src = (i < 1024) ? bq : (i < 2048 ? bk : bv);
      long off = i & 1023;
      *(float4*)&bcat[i] = *(const float4*)&src[off];
    }
  }
}

// ---------------------------------------------------------------------------
// mid: per (b, 32x32 tile): E = exp(k+w) row-major; vT, EKT transposed.
// ---------------------------------------------------------------------------
__global__ void mid(const ushort* __restrict__ qkv, const float* __restrict__ w,
                    ushort* __restrict__ E, ushort* __restrict__ vT,
                    ushort* __restrict__ EKT)
{
  __shared__ float tk[32][33];
  __shared__ float tv[32][33];
  int b  = blockIdx.z;
  int s0 = blockIdx.y * 32, d0 = blockIdx.x * 32;
  int tx = threadIdx.x, ty = threadIdx.y;     // (32,8)
#pragma unroll
  for (int i = 0; i < 4; ++i) {
    int s = s0 + ty + i * 8;
    long base = ((long)(b * 1024 + s)) * 3072;
    float kf = bf2f(qkv[base + 1024 + d0 + tx]);
    float vf = bf2f(qkv[base + 2048 + d0 + tx]);
    tk[ty + i * 8][tx] = expf(kf);
    tv[ty + i * 8][tx] = vf;
    float wv = w[(long)s * 1024 + d0 + tx];
    E[((long)(b * 1024 + s)) * 1024 + d0 + tx] = f2bf(expf(kf + wv));
  }
  __syncthreads();
#pragma unroll
  for (int i = 0; i < 4; ++i) {
    int d = d0 + ty + i * 8;
    long o = ((long)b * 1024 + d) * 1024 + s0 + tx;
    EKT[o] = f2bf(tk[tx][ty + i * 8]);
    vT [o] = f2bf(tv[tx][ty + i * 8]);
  }
}

// y = sigmoid(q) * num / den   (q from qkv cols [0,1024))
__global__ void ew_y(const ushort* __restrict__ qkv, const ushort* __restrict__ num,
                     const ushort* __restrict__ den, ushort* __restrict__ y)
{
  long e4 = ((long)blockIdx.x * 256 + threadIdx.x) * 4;
  long m = e4 >> 10;
  int  d = (int)(e4 & 1023);
  ushort4 q4 = *(const ushort4*)&qkv[m * 3072 + d];
  ushort4 n4 = *(const ushort4*)&num[e4];
  ushort4 d4 = *(const ushort4*)&den[e4];
  ushort4 o;
  { float qv = bf2f(q4.x), s = 1.f / (1.f + expf(-qv)); o.x = f2bf(s * bf2f(n4.x) / bf2f(d4.x)); }
  { float qv = bf2f(q4.y), s = 1.f / (1.f + expf(-qv)); o.y = f2bf(s * bf2f(n4.y) / bf2f(d4.y)); }
  { float qv = bf2f(q4.z), s = 1.f / (1.f + expf(-qv)); o.z = f2bf(s * bf2f(n4.z) / bf2f(d4.z)); }
  { float qv = bf2f(q4.w), s = 1.f / (1.f + expf(-qv)); o.w = f2bf(s * bf2f(n4.w) / bf2f(d4.w)); }
  *(ushort4*)&y[e4] = o;
}

// ---------------------------------------------------------------------------
extern "C" void kernel_launch(void* const* d_in, const int* in_sizes, int n_in,
                              void* d_out, int out_size, void* d_ws, size_t ws_size,
                              hipStream_t stream)
{
  const float* x     = (const float*)d_in[0];
  const float* wq_w  = (const float*)d_in[1];
  const float* wq_b  = (const float*)d_in[2];
  const float* wk_w  = (const float*)d_in[3];
  const float* wk_b  = (const float*)d_in[4];
  const float* wv_w  = (const float*)d_in[5];
  const float* wv_b  = (const float*)d_in[6];
  const float* w     = (const float*)d_in[7];
  const float* out_w = (const float*)d_in[8];
  const float* out_b = (const float*)d_in[9];
  float* out = (float*)d_out;

  const long MB = 1048576;
  char* ws = (char*)d_ws;
  size_t o = 0;
  auto alloc = [&](size_t bytes){ size_t r = o; o += (bytes + 255) & ~(size_t)255; return r; };

  ushort* xb   = (ushort*)(ws + alloc(8192 * 1024 * 2));
  ushort* wcat = (ushort*)(ws + alloc(3072 * 1024 * 2));
  ushort* owb  = (ushort*)(ws + alloc(1024 * 1024 * 2));
  ushort* ewb  = (ushort*)(ws + alloc(1024 * 1024 * 2));
  float*  bcat = (float*) (ws + alloc(3072 * 4));
  ushort* qkvb = (ushort*)(ws + alloc(8192 * 3072 * 2));
  ushort* Eb   = (ushort*)(ws + alloc(8 * MB * 2));
  ushort* vTb  = (ushort*)(ws + alloc(8 * MB * 2));
  ushort* EKTb = (ushort*)(ws + alloc(8 * MB * 2));
  ushort* numb = (ushort*)(ws + alloc(8 * MB * 2));
  ushort* denb = (ushort*)(ws + alloc(8 * MB * 2));
  ushort* yb   = (ushort*)(ws + alloc(8 * MB * 2));
  (void)ws_size; (void)in_sizes; (void)n_in; (void)out_size;

  // 1. all input conversions in one launch (13315*1024 = 8M + 5M + 3072 elems)
  prep_all<<<13315, 256, 0, stream>>>(x, wq_w, wk_w, wv_w, out_w, w,
                                      wq_b, wk_b, wv_b,
                                      xb, wcat, owb, ewb, bcat);

  // 2. qkv = x @ wcat^T + bcat : M=8192 N=3072 K=1024 (1536 blocks)
  gemm_bt<0><<<dim3(24, 64, 1), 256, 0, stream>>>(
      xb, 0, wcat, 0, qkvb, 0, bcat,
      xb, 0, wcat, 0, qkvb, 0, bcat,
      3072, 1024, 1);

  // 3. E = exp(k+w); vT = v^T; EKT = exp(k)^T
  mid<<<dim3(32, 32, 8), dim3(32, 8), 0, stream>>>(qkvb, w, Eb, vTb, EKTb);

  // 4. z<8: num[b] = E[b] @ vT[b]^T ; z>=8: den[b] = exp(w) @ EKT[b]^T
  //    (1024 blocks, full machine)
  gemm_bt<0><<<dim3(8, 8, 16), 256, 0, stream>>>(
      Eb,  MB, vTb,  MB, numb, MB, nullptr,
      ewb, 0,  EKTb, MB, denb, MB, nullptr,
      1024, 1024, 8);

  // 5. y = sigmoid(q) * num / den
  ew_y<<<8192, 256, 0, stream>>>(qkvb, numb, denb, yb);

  // 6. out = y @ out_w^T + out_b : M=8192 N=1024 K=1024, fp32 store (512 blocks)
  gemm_bt<1><<<dim3(8, 64, 1), 256, 0, stream>>>(
      yb, 0, owb, 0, out, 0, out_b,
      yb, 0, owb, 0, out, 0, out_b,
      1024, 1024, 1);
}